// Round 1
// baseline (4149.451 us; speedup 1.0000x reference)
//
#include <hip/hip_runtime.h>
#include <cstdint>
#include <cstddef>

static constexpr int NN = 100000;   // nodes per type
static constexpr int EE = 500000;   // edges per relation
static constexpr int DD = 128;      // feature dim (in == out)

// relation j: source type ST[j] -> destination type DT[j]
static const int ST[4] = {0, 1, 2, 0};
static const int DT[4] = {1, 2, 0, 2};

// ---------------------------------------------------------------------------
// Edge scatter: mean-aggregation numerator (sum) + count, via fp32 atomics.
// 32 lanes per edge, one float4 per lane -> 512B contiguous read per edge.
// ---------------------------------------------------------------------------
__global__ __launch_bounds__(256)
void scatter_mean(const float* __restrict__ x,
                  const int* __restrict__ src,
                  const int* __restrict__ dst,
                  float* __restrict__ agg,
                  float* __restrict__ cnt,
                  int nE) {
    int gid  = blockIdx.x * 256 + threadIdx.x;
    int e    = gid >> 5;
    if (e >= nE) return;
    int lane = gid & 31;
    int s = src[e];
    int d = dst[e];
    float4 v = ((const float4*)(x + (size_t)s * DD))[lane];
    float* o = agg + (size_t)d * DD + lane * 4;
    atomicAdd(o + 0, v.x);
    atomicAdd(o + 1, v.y);
    atomicAdd(o + 2, v.z);
    atomicAdd(o + 3, v.w);
    if (lane == 0) atomicAdd(cnt + d, 1.0f);
}

// ---------------------------------------------------------------------------
// Fused multi-operand SGEMM: C[row][col] (=, or +=) sum_p  Ap_scaled @ Wp^T  (+ bias)
//   Ap: [M][128] row-major. Wp: [128][128] row-major (out x in) -> we need Wp^T.
//   For operands with cp != nullptr, rows of Ap are scaled by 1/cnt (0 if cnt==0).
// Tile: 128 rows x 128 cols per block, 256 threads, 8x8 micro-tile, BK=8.
// Column mapping per thread: col(j) = tx*4 + (j&3) + 64*(j>>2)  (2-way LDS banks = free)
// ---------------------------------------------------------------------------
__global__ __launch_bounds__(256)
void fused_gemm(const float* __restrict__ A0, const float* __restrict__ W0, const float* __restrict__ c0,
                const float* __restrict__ A1, const float* __restrict__ W1, const float* __restrict__ c1,
                const float* __restrict__ A2, const float* __restrict__ W2, const float* __restrict__ c2,
                int P,
                const float* __restrict__ bias,
                float* __restrict__ C, int M, int accum) {
    __shared__ float As[8][132];
    __shared__ float Bs[8][132];

    float acc[8][8];
#pragma unroll
    for (int i = 0; i < 8; ++i)
#pragma unroll
        for (int j = 0; j < 8; ++j) acc[i][j] = 0.f;

    const int tid  = threadIdx.x;
    const int tx   = tid & 15;
    const int ty   = tid >> 4;
    const int row0 = blockIdx.x * 128;
    const int lm   = tid >> 1;         // 0..127: tile row (A) / out-col (W)
    const int lk   = (tid & 1) * 4;    // 0 or 4: k sub-offset
    const int grow = row0 + lm;
    const bool rvalid = grow < M;

    for (int p = 0; p < P; ++p) {
        const float* A  = (p == 0) ? A0 : (p == 1) ? A1 : A2;
        const float* W  = (p == 0) ? W0 : (p == 1) ? W1 : W2;
        const float* cp = (p == 0) ? c0 : (p == 1) ? c1 : c2;
        float scale = 1.0f;
        if (cp) {
            float c = rvalid ? cp[grow] : 0.0f;
            scale = (c > 0.f) ? (1.0f / c) : 0.0f;
        }
        for (int k0 = 0; k0 < DD; k0 += 8) {
            float4 av = make_float4(0.f, 0.f, 0.f, 0.f);
            if (rvalid) av = *(const float4*)(A + (size_t)grow * DD + k0 + lk);
            float4 wv = *(const float4*)(W + (size_t)lm * DD + k0 + lk);
            av.x *= scale; av.y *= scale; av.z *= scale; av.w *= scale;

            __syncthreads();   // protect prior iteration's LDS reads
            As[lk + 0][lm] = av.x;
            As[lk + 1][lm] = av.y;
            As[lk + 2][lm] = av.z;
            As[lk + 3][lm] = av.w;
            Bs[lk + 0][lm] = wv.x;
            Bs[lk + 1][lm] = wv.y;
            Bs[lk + 2][lm] = wv.z;
            Bs[lk + 3][lm] = wv.w;
            __syncthreads();

#pragma unroll
            for (int kk = 0; kk < 8; ++kk) {
                float a[8], b[8];
#pragma unroll
                for (int i = 0; i < 8; ++i) a[i] = As[kk][ty * 8 + i];
#pragma unroll
                for (int j = 0; j < 8; ++j) b[j] = Bs[kk][tx * 4 + (j & 3) + ((j >> 2) << 6)];
#pragma unroll
                for (int i = 0; i < 8; ++i)
#pragma unroll
                    for (int j = 0; j < 8; ++j)
                        acc[i][j] = fmaf(a[i], b[j], acc[i][j]);
            }
        }
    }

    float bv[8];
#pragma unroll
    for (int j = 0; j < 8; ++j)
        bv[j] = bias ? bias[tx * 4 + (j & 3) + ((j >> 2) << 6)] : 0.0f;

#pragma unroll
    for (int i = 0; i < 8; ++i) {
        int row = row0 + ty * 8 + i;
        if (row < M) {
            float* cp0 = C + (size_t)row * DD + tx * 4;        // cols tx*4 .. +3
            float* cp1 = cp0 + 64;                              // cols tx*4+64 .. +3
            if (accum) {
#pragma unroll
                for (int j = 0; j < 4; ++j) cp0[j] += acc[i][j] + bv[j];
#pragma unroll
                for (int j = 0; j < 4; ++j) cp1[j] += acc[i][4 + j] + bv[4 + j];
            } else {
                *(float4*)cp0 = make_float4(acc[i][0] + bv[0], acc[i][1] + bv[1],
                                            acc[i][2] + bv[2], acc[i][3] + bv[3]);
                *(float4*)cp1 = make_float4(acc[i][4] + bv[4], acc[i][5] + bv[5],
                                            acc[i][6] + bv[6], acc[i][7] + bv[7]);
            }
        }
    }
}

// ---------------------------------------------------------------------------
extern "C" void kernel_launch(void* const* d_in, const int* in_sizes, int n_in,
                              void* d_out, int out_size, void* d_ws, size_t ws_size,
                              hipStream_t stream) {
    const float* x[3];
    const float* wroot[3];
    const float* broot[3];
    const float* wrel[4];
    const int*   srcp[4];
    const int*   dstp[4];
    for (int t = 0; t < 3; ++t) {
        x[t]     = (const float*)d_in[3 * t + 0];
        wroot[t] = (const float*)d_in[3 * t + 1];
        broot[t] = (const float*)d_in[3 * t + 2];
    }
    for (int j = 0; j < 4; ++j) {
        wrel[j] = (const float*)d_in[9 + 3 * j + 0];
        srcp[j] = (const int*)  d_in[9 + 3 * j + 1];
        dstp[j] = (const int*)  d_in[9 + 3 * j + 2];
    }
    float* out[3] = { (float*)d_out,
                      (float*)d_out + (size_t)NN * DD,
                      (float*)d_out + 2 * (size_t)NN * DD };

    const size_t aggBytes = (size_t)NN * DD * sizeof(float);  // 51.2 MB
    const size_t cntBytes = (size_t)NN * sizeof(float);       // 0.4 MB
    const size_t fullNeed = 4 * aggBytes + 4 * cntBytes;      // ~206 MB

    const int gemmGrid = (NN + 127) / 128;          // 782
    const int scatGrid = (EE * 32 + 255) / 256;     // 62500

    if (ws_size >= fullNeed) {
        // ---- fused path: all 4 aggregations, then 3 multi-operand GEMMs ----
        char* p = (char*)d_ws;
        float* agg[4];
        float* cnt[4];
        for (int j = 0; j < 4; ++j) agg[j] = (float*)(p + (size_t)j * aggBytes);
        float* cntBase = (float*)(p + 4 * aggBytes);
        for (int j = 0; j < 4; ++j) cnt[j] = cntBase + (size_t)j * NN;

        hipMemsetAsync(d_ws, 0, fullNeed, stream);

        for (int j = 0; j < 4; ++j)
            scatter_mean<<<scatGrid, 256, 0, stream>>>(x[ST[j]], srcp[j], dstp[j],
                                                       agg[j], cnt[j], EE);

        // type0 <- root0 + rel2 ; type1 <- root1 + rel0 ; type2 <- root2 + rel1 + rel3
        fused_gemm<<<gemmGrid, 256, 0, stream>>>(
            x[0], wroot[0], nullptr, agg[2], wrel[2], cnt[2],
            nullptr, nullptr, nullptr, 2, broot[0], out[0], NN, 0);
        fused_gemm<<<gemmGrid, 256, 0, stream>>>(
            x[1], wroot[1], nullptr, agg[0], wrel[0], cnt[0],
            nullptr, nullptr, nullptr, 2, broot[1], out[1], NN, 0);
        fused_gemm<<<gemmGrid, 256, 0, stream>>>(
            x[2], wroot[2], nullptr, agg[1], wrel[1], cnt[1],
            agg[3], wrel[3], cnt[3], 3, broot[2], out[2], NN, 0);
    } else {
        // ---- sequential fallback: one agg buffer, accumulate into out ----
        float* agg = (float*)d_ws;
        float* cnt = (float*)((char*)d_ws + aggBytes);

        for (int t = 0; t < 3; ++t)
            fused_gemm<<<gemmGrid, 256, 0, stream>>>(
                x[t], wroot[t], nullptr, nullptr, nullptr, nullptr,
                nullptr, nullptr, nullptr, 1, broot[t], out[t], NN, 0);

        for (int j = 0; j < 4; ++j) {
            hipMemsetAsync(d_ws, 0, aggBytes + cntBytes, stream);
            scatter_mean<<<scatGrid, 256, 0, stream>>>(x[ST[j]], srcp[j], dstp[j],
                                                       agg, cnt, EE);
            fused_gemm<<<gemmGrid, 256, 0, stream>>>(
                agg, wrel[j], cnt, nullptr, nullptr, nullptr,
                nullptr, nullptr, nullptr, 1, nullptr, out[DT[j]], NN, 1);
        }
    }
}

// Round 2
// 1165.779 us; speedup vs baseline: 3.5594x; 3.5594x over previous
//
#include <hip/hip_runtime.h>
#include <cstdint>
#include <cstddef>

static constexpr int NN = 100000;   // nodes per type
static constexpr int EE = 500000;   // edges per relation
static constexpr int DD = 128;      // feature dim (in == out)
static constexpr int NBLK = (NN + 1023) / 1024;   // 98 scan blocks per relation

// relation j: source type ST[j] -> destination type DT[j]
static const int ST[4] = {0, 1, 2, 0};
static const int DT[4] = {1, 2, 0, 2};

// ===========================================================================
// CSR-build pipeline (per relation, batched via blockIdx.y = rel)
// ===========================================================================

__global__ __launch_bounds__(256)
void edge_hist(const int* __restrict__ d0, const int* __restrict__ d1,
               const int* __restrict__ d2, const int* __restrict__ d3,
               int* __restrict__ cnts) {
    int rel = blockIdx.y;
    const int* dst = (rel == 0) ? d0 : (rel == 1) ? d1 : (rel == 2) ? d2 : d3;
    int e = blockIdx.x * 256 + threadIdx.x;
    if (e >= EE) return;
    atomicAdd(&cnts[(size_t)rel * NN + dst[e]], 1);
}

// block sums of 1024-element chunks of cnts
__global__ __launch_bounds__(256)
void scan_k1(const int* __restrict__ cnts, int* __restrict__ bsum) {
    __shared__ int red[256];
    int rel = blockIdx.y, blk = blockIdx.x, t = threadIdx.x;
    int base = blk * 1024 + t * 4;
    int tsum = 0;
#pragma unroll
    for (int i = 0; i < 4; ++i) {
        int idx = base + i;
        if (idx < NN) tsum += cnts[(size_t)rel * NN + idx];
    }
    red[t] = tsum;
    __syncthreads();
    for (int o = 128; o > 0; o >>= 1) {
        if (t < o) red[t] += red[t + o];
        __syncthreads();
    }
    if (t == 0) bsum[rel * NBLK + blk] = red[0];
}

// in-place exclusive scan of the NBLK block sums (single thread per rel; NBLK=98)
__global__ void scan_k2(int* __restrict__ bsum) {
    int rel = blockIdx.y;
    if (threadIdx.x != 0) return;
    int run = 0;
    for (int i = 0; i < NBLK; ++i) {
        int v = bsum[rel * NBLK + i];
        bsum[rel * NBLK + i] = run;
        run += v;
    }
}

// final exclusive scan: offs[] and a working copy work[] for the scatter bump
__global__ __launch_bounds__(256)
void scan_k3(const int* __restrict__ cnts, const int* __restrict__ bsum,
             int* __restrict__ offs, int* __restrict__ work) {
    __shared__ int sdata[256];
    int rel = blockIdx.y, blk = blockIdx.x, t = threadIdx.x;
    int base = blk * 1024 + t * 4;
    int e[4];
    int tsum = 0;
#pragma unroll
    for (int i = 0; i < 4; ++i) {
        int idx = base + i;
        e[i] = (idx < NN) ? cnts[(size_t)rel * NN + idx] : 0;
        tsum += e[i];
    }
    sdata[t] = tsum;
    __syncthreads();
    for (int o = 1; o < 256; o <<= 1) {
        int v = 0;
        if (t >= o) v = sdata[t - o];
        __syncthreads();
        if (t >= o) sdata[t] += v;
        __syncthreads();
    }
    int run = bsum[rel * NBLK + blk] + (sdata[t] - tsum);
#pragma unroll
    for (int i = 0; i < 4; ++i) {
        int idx = base + i;
        if (idx < NN) {
            offs[(size_t)rel * NN + idx] = run;
            work[(size_t)rel * NN + idx] = run;
        }
        run += e[i];
    }
}

__global__ __launch_bounds__(256)
void edge_scatter(const int* __restrict__ s0, const int* __restrict__ s1,
                  const int* __restrict__ s2, const int* __restrict__ s3,
                  const int* __restrict__ d0, const int* __restrict__ d1,
                  const int* __restrict__ d2, const int* __restrict__ d3,
                  int* __restrict__ work, int* __restrict__ sorted) {
    int rel = blockIdx.y;
    const int* src = (rel == 0) ? s0 : (rel == 1) ? s1 : (rel == 2) ? s2 : s3;
    const int* dst = (rel == 0) ? d0 : (rel == 1) ? d1 : (rel == 2) ? d2 : d3;
    int e = blockIdx.x * 256 + threadIdx.x;
    if (e >= EE) return;
    int d = dst[e];
    int pos = atomicAdd(&work[(size_t)rel * NN + d], 1);
    sorted[(size_t)rel * EE + pos] = src[e];
}

// pull-aggregation: one 64-lane wave per destination node; mean written once,
// deg==0 rows written as zeros (so no memset of agg needed).
__global__ __launch_bounds__(256)
void csr_aggregate(const float* __restrict__ x0, const float* __restrict__ x1,
                   const float* __restrict__ x2,
                   const int* __restrict__ sorted, const int* __restrict__ cnts,
                   const int* __restrict__ offs, float* __restrict__ agg) {
    int rel = blockIdx.y;
    const float* x = (rel == 0) ? x0 : (rel == 1) ? x1 : (rel == 2) ? x2 : x0;
    int node = blockIdx.x * 4 + (threadIdx.x >> 6);
    if (node >= NN) return;
    int lane = threadIdx.x & 63;
    const int* srt = sorted + (size_t)rel * EE;
    int deg = cnts[(size_t)rel * NN + node];
    int off = offs[(size_t)rel * NN + node];
    float sx = 0.f, sy = 0.f;
    for (int k = 0; k < deg; ++k) {
        int s = srt[off + k];                       // uniform across wave -> broadcast
        float2 v = *(const float2*)(x + (size_t)s * DD + lane * 2);
        sx += v.x; sy += v.y;
    }
    float scale = (deg > 0) ? (1.0f / (float)deg) : 0.0f;
    float2 o = make_float2(sx * scale, sy * scale);
    *(float2*)(agg + (size_t)rel * NN * DD + (size_t)node * DD + lane * 2) = o;
}

// ===========================================================================
// Legacy atomic scatter (fallback only)
// ===========================================================================
__global__ __launch_bounds__(256)
void scatter_mean(const float* __restrict__ x,
                  const int* __restrict__ src,
                  const int* __restrict__ dst,
                  float* __restrict__ agg,
                  float* __restrict__ cnt,
                  int nE) {
    int gid  = blockIdx.x * 256 + threadIdx.x;
    int e    = gid >> 5;
    if (e >= nE) return;
    int lane = gid & 31;
    int s = src[e];
    int d = dst[e];
    float4 v = ((const float4*)(x + (size_t)s * DD))[lane];
    float* o = agg + (size_t)d * DD + lane * 4;
    atomicAdd(o + 0, v.x);
    atomicAdd(o + 1, v.y);
    atomicAdd(o + 2, v.z);
    atomicAdd(o + 3, v.w);
    if (lane == 0) atomicAdd(cnt + d, 1.0f);
}

// ===========================================================================
// Fused multi-operand SGEMM: C (=, or +=) sum_p  Ap_scaled @ Wp^T (+ bias)
// 128x128 tile, 256 threads, 8x8 micro-tile, BK=8.
// ===========================================================================
__global__ __launch_bounds__(256)
void fused_gemm(const float* __restrict__ A0, const float* __restrict__ W0, const float* __restrict__ c0,
                const float* __restrict__ A1, const float* __restrict__ W1, const float* __restrict__ c1,
                const float* __restrict__ A2, const float* __restrict__ W2, const float* __restrict__ c2,
                int P,
                const float* __restrict__ bias,
                float* __restrict__ C, int M, int accum) {
    __shared__ float As[8][132];
    __shared__ float Bs[8][132];

    float acc[8][8];
#pragma unroll
    for (int i = 0; i < 8; ++i)
#pragma unroll
        for (int j = 0; j < 8; ++j) acc[i][j] = 0.f;

    const int tid  = threadIdx.x;
    const int tx   = tid & 15;
    const int ty   = tid >> 4;
    const int row0 = blockIdx.x * 128;
    const int lm   = tid >> 1;
    const int lk   = (tid & 1) * 4;
    const int grow = row0 + lm;
    const bool rvalid = grow < M;

    for (int p = 0; p < P; ++p) {
        const float* A  = (p == 0) ? A0 : (p == 1) ? A1 : A2;
        const float* W  = (p == 0) ? W0 : (p == 1) ? W1 : W2;
        const float* cp = (p == 0) ? c0 : (p == 1) ? c1 : c2;
        float scale = 1.0f;
        if (cp) {
            float c = rvalid ? cp[grow] : 0.0f;
            scale = (c > 0.f) ? (1.0f / c) : 0.0f;
        }
        for (int k0 = 0; k0 < DD; k0 += 8) {
            float4 av = make_float4(0.f, 0.f, 0.f, 0.f);
            if (rvalid) av = *(const float4*)(A + (size_t)grow * DD + k0 + lk);
            float4 wv = *(const float4*)(W + (size_t)lm * DD + k0 + lk);
            av.x *= scale; av.y *= scale; av.z *= scale; av.w *= scale;

            __syncthreads();
            As[lk + 0][lm] = av.x;
            As[lk + 1][lm] = av.y;
            As[lk + 2][lm] = av.z;
            As[lk + 3][lm] = av.w;
            Bs[lk + 0][lm] = wv.x;
            Bs[lk + 1][lm] = wv.y;
            Bs[lk + 2][lm] = wv.z;
            Bs[lk + 3][lm] = wv.w;
            __syncthreads();

#pragma unroll
            for (int kk = 0; kk < 8; ++kk) {
                float a[8], b[8];
#pragma unroll
                for (int i = 0; i < 8; ++i) a[i] = As[kk][ty * 8 + i];
#pragma unroll
                for (int j = 0; j < 8; ++j) b[j] = Bs[kk][tx * 4 + (j & 3) + ((j >> 2) << 6)];
#pragma unroll
                for (int i = 0; i < 8; ++i)
#pragma unroll
                    for (int j = 0; j < 8; ++j)
                        acc[i][j] = fmaf(a[i], b[j], acc[i][j]);
            }
        }
    }

    float bv[8];
#pragma unroll
    for (int j = 0; j < 8; ++j)
        bv[j] = bias ? bias[tx * 4 + (j & 3) + ((j >> 2) << 6)] : 0.0f;

#pragma unroll
    for (int i = 0; i < 8; ++i) {
        int row = row0 + ty * 8 + i;
        if (row < M) {
            float* cp0 = C + (size_t)row * DD + tx * 4;
            float* cp1 = cp0 + 64;
            if (accum) {
#pragma unroll
                for (int j = 0; j < 4; ++j) cp0[j] += acc[i][j] + bv[j];
#pragma unroll
                for (int j = 0; j < 4; ++j) cp1[j] += acc[i][4 + j] + bv[4 + j];
            } else {
                *(float4*)cp0 = make_float4(acc[i][0] + bv[0], acc[i][1] + bv[1],
                                            acc[i][2] + bv[2], acc[i][3] + bv[3]);
                *(float4*)cp1 = make_float4(acc[i][4] + bv[4], acc[i][5] + bv[5],
                                            acc[i][6] + bv[6], acc[i][7] + bv[7]);
            }
        }
    }
}

// ===========================================================================
extern "C" void kernel_launch(void* const* d_in, const int* in_sizes, int n_in,
                              void* d_out, int out_size, void* d_ws, size_t ws_size,
                              hipStream_t stream) {
    const float* x[3];
    const float* wroot[3];
    const float* broot[3];
    const float* wrel[4];
    const int*   srcp[4];
    const int*   dstp[4];
    for (int t = 0; t < 3; ++t) {
        x[t]     = (const float*)d_in[3 * t + 0];
        wroot[t] = (const float*)d_in[3 * t + 1];
        broot[t] = (const float*)d_in[3 * t + 2];
    }
    for (int j = 0; j < 4; ++j) {
        wrel[j] = (const float*)d_in[9 + 3 * j + 0];
        srcp[j] = (const int*)  d_in[9 + 3 * j + 1];
        dstp[j] = (const int*)  d_in[9 + 3 * j + 2];
    }
    float* out[3] = { (float*)d_out,
                      (float*)d_out + (size_t)NN * DD,
                      (float*)d_out + 2 * (size_t)NN * DD };

    const size_t aggBytes  = (size_t)NN * DD * sizeof(float);   // 51.2 MB
    const size_t intN      = ((size_t)NN * sizeof(int) + 255) & ~(size_t)255;
    const size_t intE      = ((size_t)EE * sizeof(int) + 255) & ~(size_t)255;
    const size_t bsumBytes = ((size_t)4 * NBLK * sizeof(int) + 255) & ~(size_t)255;

    // CSR-path layout: agg[4] | cnt_i[4] | work[4] | offs[4] | bsum | sorted[4]
    const size_t need1 = 4 * aggBytes + 3 * (4 * intN) + bsumBytes + 4 * intE;
    const size_t cntBytesF = (size_t)NN * sizeof(float);
    const size_t need0 = 4 * aggBytes + 4 * cntBytesF;          // legacy fused path

    const int gemmGrid = (NN + 127) / 128;
    const int edgeGrid = (EE + 255) / 256;

    if (ws_size >= need1) {
        // ---- CSR path: counting-sort by dst, then pull-aggregation, no fp32 atomics
        char* p = (char*)d_ws;
        float* agg    = (float*)p;                 p += 4 * aggBytes;
        int*   cnts   = (int*)p;                   p += 4 * intN;
        int*   work   = (int*)p;                   p += 4 * intN;
        int*   offs   = (int*)p;                   p += 4 * intN;
        int*   bsum   = (int*)p;                   p += bsumBytes;
        int*   sorted = (int*)p;

        hipMemsetAsync(cnts, 0, 4 * intN, stream);

        dim3 eg(edgeGrid, 4);
        edge_hist<<<eg, 256, 0, stream>>>(dstp[0], dstp[1], dstp[2], dstp[3], cnts);
        scan_k1<<<dim3(NBLK, 4), 256, 0, stream>>>(cnts, bsum);
        scan_k2<<<dim3(1, 4), 64, 0, stream>>>(bsum);
        scan_k3<<<dim3(NBLK, 4), 256, 0, stream>>>(cnts, bsum, offs, work);
        edge_scatter<<<eg, 256, 0, stream>>>(srcp[0], srcp[1], srcp[2], srcp[3],
                                             dstp[0], dstp[1], dstp[2], dstp[3],
                                             work, sorted);
        csr_aggregate<<<dim3((NN + 3) / 4, 4), 256, 0, stream>>>(
            x[0], x[1], x[2], sorted, cnts, offs, agg);

        float* a0 = agg;                      // rel0 agg
        float* a1 = agg + (size_t)NN * DD;    // rel1
        float* a2 = agg + 2 * (size_t)NN * DD;
        float* a3 = agg + 3 * (size_t)NN * DD;

        // type0 <- root0 + rel2 ; type1 <- root1 + rel0 ; type2 <- root2 + rel1 + rel3
        fused_gemm<<<gemmGrid, 256, 0, stream>>>(
            x[0], wroot[0], nullptr, a2, wrel[2], nullptr,
            nullptr, nullptr, nullptr, 2, broot[0], out[0], NN, 0);
        fused_gemm<<<gemmGrid, 256, 0, stream>>>(
            x[1], wroot[1], nullptr, a0, wrel[0], nullptr,
            nullptr, nullptr, nullptr, 2, broot[1], out[1], NN, 0);
        fused_gemm<<<gemmGrid, 256, 0, stream>>>(
            x[2], wroot[2], nullptr, a1, wrel[1], nullptr,
            a3, wrel[3], nullptr, 3, broot[2], out[2], NN, 0);
    } else if (ws_size >= need0) {
        // ---- legacy fused atomic path ----
        char* p = (char*)d_ws;
        float* agg[4];
        float* cnt[4];
        for (int j = 0; j < 4; ++j) agg[j] = (float*)(p + (size_t)j * aggBytes);
        float* cntBase = (float*)(p + 4 * aggBytes);
        for (int j = 0; j < 4; ++j) cnt[j] = cntBase + (size_t)j * NN;

        hipMemsetAsync(d_ws, 0, need0, stream);
        const int scatGrid = (EE * 32 + 255) / 256;
        for (int j = 0; j < 4; ++j)
            scatter_mean<<<scatGrid, 256, 0, stream>>>(x[ST[j]], srcp[j], dstp[j],
                                                       agg[j], cnt[j], EE);
        fused_gemm<<<gemmGrid, 256, 0, stream>>>(
            x[0], wroot[0], nullptr, agg[2], wrel[2], cnt[2],
            nullptr, nullptr, nullptr, 2, broot[0], out[0], NN, 0);
        fused_gemm<<<gemmGrid, 256, 0, stream>>>(
            x[1], wroot[1], nullptr, agg[0], wrel[0], cnt[0],
            nullptr, nullptr, nullptr, 2, broot[1], out[1], NN, 0);
        fused_gemm<<<gemmGrid, 256, 0, stream>>>(
            x[2], wroot[2], nullptr, agg[1], wrel[1], cnt[1],
            agg[3], wrel[3], cnt[3], 3, broot[2], out[2], NN, 0);
    } else {
        // ---- sequential fallback ----
        float* agg = (float*)d_ws;
        float* cnt = (float*)((char*)d_ws + aggBytes);
        const int scatGrid = (EE * 32 + 255) / 256;

        for (int t = 0; t < 3; ++t)
            fused_gemm<<<gemmGrid, 256, 0, stream>>>(
                x[t], wroot[t], nullptr, nullptr, nullptr, nullptr,
                nullptr, nullptr, nullptr, 1, broot[t], out[t], NN, 0);

        for (int j = 0; j < 4; ++j) {
            hipMemsetAsync(d_ws, 0, aggBytes + cntBytesF, stream);
            scatter_mean<<<scatGrid, 256, 0, stream>>>(x[ST[j]], srcp[j], dstp[j],
                                                       agg, cnt, EE);
            fused_gemm<<<gemmGrid, 256, 0, stream>>>(
                agg, wrel[j], cnt, nullptr, nullptr, nullptr,
                nullptr, nullptr, nullptr, 1, nullptr, out[DT[j]], NN, 1);
        }
    }
}